// Round 15
// baseline (652.895 us; speedup 1.0000x reference)
//
#include <hip/hip_runtime.h>
#include <stdint.h>

typedef float f32x4 __attribute__((ext_vector_type(4)));

__device__ __forceinline__ float sigm(float x){ return 1.f/(1.f + __expf(-x)); }

// ---------------- embedding gather ----------------
__global__ void k_gather(const float* __restrict__ emb, const int* __restrict__ atoms,
                         float* __restrict__ h){
  int gid = blockIdx.x*256 + threadIdx.x;   // < 524288
  int i = gid >> 7, k = gid & 127;
  h[gid] = emb[atoms[i]*128 + k];
}

// ---------------- WcT[e][g] = (w_ih @ lin_w)[g][e]  (128 x 384) ----------------
__global__ void k_wc(const float* __restrict__ w_ih, const float* __restrict__ lin_w,
                     float* __restrict__ WcT){
  int idx = blockIdx.x*256 + threadIdx.x;   // < 49152
  int g = idx >> 7, e = idx & 127;
  float s = 0.f;
  for (int d = 0; d < 128; d++) s += w_ih[g*128+d]*lin_w[d*128+e];
  WcT[e*384 + g] = s;
}

// ---------------- WhhT[e][g] = w_hh[g][e] ----------------
__global__ void k_trT(const float* __restrict__ w_hh, float* __restrict__ WhhT){
  int idx = blockIdx.x*256 + threadIdx.x;   // < 49152
  int g = idx >> 7, e = idx & 127;
  WhhT[e*384 + g] = w_hh[g*128 + e];
}

// ---------------- bc = w_ih @ lin_b + b_ih ----------------
__global__ void k_bc(const float* __restrict__ w_ih, const float* __restrict__ lin_b,
                     const float* __restrict__ b_ih, float* __restrict__ bc){
  int g = blockIdx.x*128 + threadIdx.x;
  if (g >= 384) return;
  float s = b_ih[g];
  for (int d = 0; d < 128; d++) s += w_ih[g*128+d]*lin_b[d];
  bc[g] = s;
}

// =====================================================================
// fp32 GEMM (round-11 proven, verbatim): part[split][M][128] =
// A[M][Kwin] @ B[K][128]. 128x128 tile, 512 threads, micro 8x4,
// BK=32 double-buffered, compiler-scheduled. VGPR 52, 2 blocks/CU.
// FINAL: 6 structural variants failed to beat this (r8-r14).
// =====================================================================
__global__ __launch_bounds__(512) void k_gemm_nt(const float* __restrict__ A,
    const float* __restrict__ B, float* __restrict__ part,
    int M, int lda, int kchunk)
{
  __shared__ float As[2][32*132];   // [kk][m] transposed A tile
  __shared__ float Bs[2][32*132];   // [kk][n]

  const int tid = threadIdx.x;
  const int m0  = blockIdx.x * 128;
  const int k0  = blockIdx.y * kchunk;
  const int chunks = kchunk >> 5;

  const int ar = tid >> 2;          // A row 0..127
  const int ac = tid & 3;           // A k-group
  const int br = tid >> 4;          // B kk row 0..31
  const int bc = tid & 15;          // B col group
  const int tn = tid & 31;          // cols tn*4
  const int tm = tid >> 5;          // rows tm*8 (2 values/wave -> broadcast reads)

  f32x4 pa[2], pb[2];

  auto load_regs = [&](int c){
    const float* Ab = A + (size_t)(m0 + ar)*lda + k0 + c*32 + ac*4;
    pa[0] = *(const f32x4*)(Ab);
    pa[1] = *(const f32x4*)(Ab + 16);
    const float* Bb = B + (size_t)(k0 + c*32 + br)*128 + bc*8;
    pb[0] = *(const f32x4*)(Bb);
    pb[1] = *(const f32x4*)(Bb + 4);
  };
  auto write_lds = [&](int buf){
    #pragma unroll
    for (int j = 0; j < 4; j++){
      As[buf][(ac*4 + j)*132 + ar]      = pa[0][j];
      As[buf][(ac*4 + 16 + j)*132 + ar] = pa[1][j];
    }
    *(f32x4*)&Bs[buf][br*132 + bc*8]     = pb[0];
    *(f32x4*)&Bs[buf][br*132 + bc*8 + 4] = pb[1];
  };

  f32x4 acc[8];
  #pragma unroll
  for (int i = 0; i < 8; i++) acc[i] = (f32x4){0,0,0,0};

  load_regs(0);
  write_lds(0);
  if (chunks > 1) load_regs(1);
  __syncthreads();

  for (int c = 0; c < chunks; ++c){
    int cur = c & 1;
    if (c+1 < chunks) write_lds(cur^1);
    const float* Ap = &As[cur][tm*8];
    const float* Bp = &Bs[cur][tn*4];
    #pragma unroll 8
    for (int kk = 0; kk < 32; kk++){
      f32x4 a0 = *(const f32x4*)(Ap + kk*132);
      f32x4 a1 = *(const f32x4*)(Ap + kk*132 + 4);
      f32x4 b  = *(const f32x4*)(Bp + kk*132);
      acc[0] += a0[0]*b; acc[1] += a0[1]*b; acc[2] += a0[2]*b; acc[3] += a0[3]*b;
      acc[4] += a1[0]*b; acc[5] += a1[1]*b; acc[6] += a1[2]*b; acc[7] += a1[3]*b;
    }
    if (c+2 < chunks) load_regs(c+2);
    __syncthreads();
  }

  float* P = part + ((size_t)blockIdx.y*M + m0 + tm*8)*128 + tn*4;
  #pragma unroll
  for (int i = 0; i < 8; i++)
    *(f32x4*)(P + (size_t)i*128) = acc[i];
}

// ---------------- sum splitK partials ----------------
__global__ void k_reduce(const float* __restrict__ part, float* __restrict__ out,
                         int nsplit, int stride4, int n4){
  int i = blockIdx.x*256 + threadIdx.x;
  if (i >= n4) return;
  const f32x4* p = (const f32x4*)part;
  f32x4 s = p[i];
  for (int sp = 1; sp < nsplit; sp++) s += p[(size_t)sp*stride4 + i];
  ((f32x4*)out)[i] = s;
}

// =====================================================================
// Fused GRU tail: replaces k_wgemm + k_gate.
// grid (64, 4), 512 threads. Block handles rows m0..m0+63, output cols
// c0..c0+31 (gate-coupled cols c0+{0,128,256} computed here).
// Stages ah^T and h^T in LDS once; 3 passes compute gi/gh slices with
// interleaved Wc/Whh L2 streams (r10-proven W-from-L2); gates in-reg;
// writes hnew. FMA k-order identical to old wgemm -> same rounding.
// =====================================================================
__global__ __launch_bounds__(512) void k_gruF(const float* __restrict__ ah,
    const float* __restrict__ h, const float* __restrict__ WcT,
    const float* __restrict__ WhhT, const float* __restrict__ bcv,
    const float* __restrict__ bhh, float* __restrict__ hnew)
{
  __shared__ float Aa[128*68];   // ah^T : [e][m]
  __shared__ float Ah[128*68];   // h^T  : [e][m]
  const int tid = threadIdx.x;
  const int m0 = blockIdx.x * 64;
  const int c0 = blockIdx.y * 32;

  for (int i4 = tid; i4 < 2048; i4 += 512){
    int r = i4 >> 5, c4 = (i4 & 31) * 4;
    f32x4 va = *(const f32x4*)(ah + (size_t)(m0 + r)*128 + c4);
    f32x4 vh = *(const f32x4*)(h  + (size_t)(m0 + r)*128 + c4);
    #pragma unroll
    for (int j = 0; j < 4; j++){
      Aa[(c4+j)*68 + r] = va[j];
      Ah[(c4+j)*68 + r] = vh[j];
    }
  }
  __syncthreads();

  const int tn = tid & 7;        // col group: c0 + tn*4
  const int tm = tid >> 3;       // row 0..63
  const int col = c0 + tn*4;

  f32x4 A0, B0;
  auto pass = [&](int s){
    f32x4 accA = {0,0,0,0}, accB = {0,0,0,0};
    const float* Wa = WcT  + s*128 + col;
    const float* Wb = WhhT + s*128 + col;
    const float* pa = &Aa[tm];
    const float* ph = &Ah[tm];
    #pragma unroll 8
    for (int k = 0; k < 128; k++){
      float xa = pa[k*68];
      float xh = ph[k*68];
      f32x4 ba = *(const f32x4*)(Wa + (size_t)k*384);
      f32x4 bb = *(const f32x4*)(Wb + (size_t)k*384);
      accA += xa*ba;
      accB += xh*bb;
    }
    A0 = accA; B0 = accB;
  };

  f32x4 rr, zz;
  pass(0);
  #pragma unroll
  for (int j = 0; j < 4; j++)
    rr[j] = sigm(A0[j] + bcv[col+j] + B0[j] + bhh[col+j]);
  pass(1);
  #pragma unroll
  for (int j = 0; j < 4; j++)
    zz[j] = sigm(A0[j] + bcv[128+col+j] + B0[j] + bhh[128+col+j]);
  pass(2);
  f32x4 o;
  #pragma unroll
  for (int j = 0; j < 4; j++){
    float n  = tanhf(A0[j] + bcv[256+col+j] + rr[j]*(B0[j] + bhh[256+col+j]));
    float hp = Ah[(col+j)*68 + tm];
    o[j] = (1.f - zz[j])*n + zz[j]*hp;
  }
  *(f32x4*)(hnew + (size_t)(m0 + tm)*128 + col) = o;
}

// ---------------- T[oc][dydx][q][k] = sum_c w1[oc][c][dydx]*m[4c+q][k]; ws1 = sum_c w1
__global__ void k_T(const float* __restrict__ c1w, const float* __restrict__ m,
                    float* __restrict__ T, float* __restrict__ ws1){
  int blk = blockIdx.x;          // 135 = oc*9 + dydx
  int oc = blk / 9, dydx = blk - oc*9;
  int tid = threadIdx.x;         // 512 = q*128 + k
  int q = tid >> 7, k = tid & 127;
  float acc = 0.f, accw = 0.f;
  for (int c = 0; c < 128; c++){
    float wv = c1w[(oc*128 + c)*9 + dydx];
    acc  += wv * m[(4*c + q)*128 + k];
    accw += wv;
  }
  T[((size_t)blk*4 + q)*128 + k] = acc;
  if (tid == 0) ws1[blk] = accw;
}

// ---------------- conv1 via algebraic factorization ----------------
__global__ __launch_bounds__(256) void k_conv1(const float* __restrict__ T,
    const float* __restrict__ ws1, const float* __restrict__ m,
    const float* __restrict__ b1, float* __restrict__ out1){
  int y = blockIdx.x >> 1;
  int x = ((blockIdx.x & 1) << 8) + threadIdx.x;
  float acc[15];
  #pragma unroll
  for (int oc = 0; oc < 15; oc++) acc[oc] = 0.f;
  #pragma unroll
  for (int dy = 0; dy < 3; dy++){
    int yy = y + dy - 1;
    if (yy < 0 || yy >= 512) continue;
    int q = yy >> 7;
    int jy = (yy & 127) * 4;
    #pragma unroll
    for (int dx = 0; dx < 3; dx++){
      int xx = x + dx - 1;
      if (xx < 0 || xx >= 512) continue;
      int k = xx & 127;
      int j = jy + (xx >> 7);
      float mv = m[j*128 + k];
      int dydx = dy*3 + dx;
      #pragma unroll
      for (int oc = 0; oc < 15; oc++)
        acc[oc] += T[((size_t)(oc*9 + dydx)*4 + q)*128 + k] + ws1[oc*9 + dydx] * mv;
    }
  }
  size_t o = (size_t)y*512 + x;
  #pragma unroll
  for (int oc = 0; oc < 15; oc++){
    float v = 0.5f*acc[oc] + b1[oc];
    out1[(size_t)oc*262144 + o] = v > 0.f ? v : 0.f;
  }
}

// ---------------- 3x3 conv, 4-px register blocking ----------------
template<int IC, int OC, bool RELU>
__global__ __launch_bounds__(128) void k_conv(const float* __restrict__ in,
    const float* __restrict__ w, const float* __restrict__ bias, float* __restrict__ out)
{
  __shared__ float xin[IC*10*66];
  int x0 = blockIdx.x * 64, y0 = blockIdx.y * 8;
  int tid = threadIdx.x;
  for (int i = tid; i < IC*10*66; i += 128){
    int ic = i / 660;
    int rem = i - ic*660;
    int iy = rem / 66;
    int ix = rem - iy*66;
    int gy = y0 + iy - 1, gx = x0 + ix - 1;
    float v = 0.f;
    if ((unsigned)gy < 512u && (unsigned)gx < 512u)
      v = in[(size_t)ic*262144 + (size_t)gy*512 + gx];
    xin[i] = v;
  }
  __syncthreads();
  int tx = tid & 15, ty = tid >> 4;
  float acc[OC][4];
  #pragma unroll
  for (int oc = 0; oc < OC; oc++){
    float b = bias[oc];
    acc[oc][0] = b; acc[oc][1] = b; acc[oc][2] = b; acc[oc][3] = b;
  }
  for (int ic = 0; ic < IC; ic++){
    #pragma unroll
    for (int dy = 0; dy < 3; dy++){
      const float* row = &xin[ic*660 + (ty+dy)*66 + tx*4];
      float r[6];
      #pragma unroll
      for (int j = 0; j < 6; j++) r[j] = row[j];
      #pragma unroll
      for (int dx = 0; dx < 3; dx++){
        #pragma unroll
        for (int oc = 0; oc < OC; oc++){
          float wv = w[(oc*IC + ic)*9 + dy*3 + dx];
          #pragma unroll
          for (int px = 0; px < 4; px++)
            acc[oc][px] += wv * r[dx+px];
        }
      }
    }
  }
  size_t o = (size_t)(y0 + ty)*512 + x0 + tx*4;
  #pragma unroll
  for (int oc = 0; oc < OC; oc++){
    f32x4 v;
    #pragma unroll
    for (int px = 0; px < 4; px++){
      float t = acc[oc][px];
      v[px] = RELU ? fmaxf(t, 0.f) : t;
    }
    *(f32x4*)(out + (size_t)oc*262144 + o) = v;
  }
}

// ---------------- final: sigmoid((o3 + o3^T_spatial)/2) ----------------
__global__ __launch_bounds__(256) void k_final(const float* __restrict__ o3, float* __restrict__ out){
  __shared__ float B[32*33];
  int c = blockIdx.z;
  int ty = blockIdx.y, tx = blockIdx.x;
  const float* base = o3 + (size_t)c*262144;
  int tid = threadIdx.x;
  {
    int rrow = tid >> 3, cc = (tid & 7) * 4;
    f32x4 v = *(const f32x4*)(base + (size_t)(tx*32 + rrow)*512 + ty*32 + cc);
    B[rrow*33 + cc + 0] = v[0];
    B[rrow*33 + cc + 1] = v[1];
    B[rrow*33 + cc + 2] = v[2];
    B[rrow*33 + cc + 3] = v[3];
  }
  __syncthreads();
  int i = tid >> 3, j0 = (tid & 7) * 4;
  f32x4 a = *(const f32x4*)(base + (size_t)(ty*32 + i)*512 + tx*32 + j0);
  f32x4 o;
  #pragma unroll
  for (int j = 0; j < 4; j++){
    float v = 0.5f*(a[j] + B[(j0+j)*33 + i]);
    o[j] = sigm(v);
  }
  *(f32x4*)(out + (size_t)c*262144 + (size_t)(ty*32 + i)*512 + tx*32 + j0) = o;
}

extern "C" void kernel_launch(void* const* d_in, const int* in_sizes, int n_in,
                              void* d_out, int out_size, void* d_ws, size_t ws_size,
                              hipStream_t stream) {
  (void)in_sizes; (void)n_in; (void)out_size;
  const float* adj   = (const float*)d_in[0];
  const float* mem   = (const float*)d_in[1];
  const float* emb   = (const float*)d_in[2];
  const float* lin_w = (const float*)d_in[3];
  const float* lin_b = (const float*)d_in[4];
  const float* w_ih  = (const float*)d_in[5];
  const float* w_hh  = (const float*)d_in[6];
  const float* b_ih  = (const float*)d_in[7];
  const float* b_hh  = (const float*)d_in[8];
  const float* c1w   = (const float*)d_in[9];
  const float* c1b   = (const float*)d_in[10];
  const float* c2w   = (const float*)d_in[11];
  const float* c2b   = (const float*)d_in[12];
  const float* c3w   = (const float*)d_in[13];
  const float* c3b   = (const float*)d_in[14];
  const int*   atoms = (const int*)d_in[15];
  char* ws = (char*)d_ws;

  // ---- runtime-selected splitK: 16 (needs 40.8 MB ws, proven) else 8 ----
  const bool big = ws_size >= 40780800u;
  const int  NS  = big ? 16 : 8;          // adjacency splits
  const int  NSm = big ? 64 : 32;         // membership splits
  const size_t partB = (size_t)NS * 2097152u;   // NS * 4096*128*4

  float* part = (float*)(ws + 0);
  float* out1 = (float*)(ws + 0);                 // 15.73MB (over dead part)
  float* out2 = (float*)(ws + 15728640);          // ..28.31MB
  float* out3 = (float*)(ws + 0);                 // over dead out1
  float* ah   = (float*)(ws + partB);
  float* h0   = (float*)(ws + partB + 2097152);
  float* h1   = (float*)(ws + partB + 4194304);
  char*  sm   = ws + partB + 6291456;
  float* WcT  = (float*)(sm);                     //   196,608
  float* WhhT = (float*)(sm + 196608);            //   196,608
  float* bc   = (float*)(sm + 393216);            //     1,536
  float* mbuf = (float*)(sm + 394752);            //   262,144
  float* Tbuf = (float*)(sm + 656896);            //   276,480
  float* ws1  = (float*)(sm + 933376);            //       768

  k_wc<<<192, 256, 0, stream>>>(w_ih, lin_w, WcT);
  k_trT<<<192, 256, 0, stream>>>(w_hh, WhhT);
  k_bc<<<3, 128, 0, stream>>>(w_ih, lin_b, b_ih, bc);
  k_gather<<<2048, 256, 0, stream>>>(emb, atoms, h0);

  float* hc = h0; float* hn = h1;
  for (int it = 0; it < 4; it++){
    k_gemm_nt<<<dim3(32, NS), 512, 0, stream>>>(adj, hc, part, 4096, 4096, 4096/NS);
    k_reduce<<<512, 256, 0, stream>>>(part, ah, NS, 131072, 131072);
    k_gruF<<<dim3(64, 4), 512, 0, stream>>>(ah, hc, WcT, WhhT, bc, b_hh, hn);
    float* t = hc; hc = hn; hn = t;
  }

  // hc == h0 after 4 iterations
  k_gemm_nt<<<dim3(4, NSm), 512, 0, stream>>>(mem, hc, part, 512, 4096, 4096/NSm);
  k_reduce<<<64, 256, 0, stream>>>(part, mbuf, NSm, 16384, 16384);
  k_T<<<135, 512, 0, stream>>>(c1w, mbuf, Tbuf, ws1);
  k_conv1<<<1024, 256, 0, stream>>>(Tbuf, ws1, mbuf, c1b, out1);
  k_conv<15,12,true><<<dim3(8,64), 128, 0, stream>>>(out1, c2w, c2b, out2);
  k_conv<12,12,false><<<dim3(8,64), 128, 0, stream>>>(out2, c3w, c3b, out3);
  k_final<<<dim3(16,16,12), 256, 0, stream>>>(out3, (float*)d_out);
}

// Round 16
// 507.110 us; speedup vs baseline: 1.2875x; 1.2875x over previous
//
#include <hip/hip_runtime.h>
#include <stdint.h>

typedef float f32x4 __attribute__((ext_vector_type(4)));

__device__ __forceinline__ float sigm(float x){ return 1.f/(1.f + __expf(-x)); }

// ---------------- embedding gather ----------------
__global__ void k_gather(const float* __restrict__ emb, const int* __restrict__ atoms,
                         float* __restrict__ h){
  int gid = blockIdx.x*256 + threadIdx.x;   // < 524288
  int i = gid >> 7, k = gid & 127;
  h[gid] = emb[atoms[i]*128 + k];
}

// ---------------- WcT[e][g] = (w_ih @ lin_w)[g][e]  (128 x 384) ----------------
__global__ void k_wc(const float* __restrict__ w_ih, const float* __restrict__ lin_w,
                     float* __restrict__ WcT){
  int idx = blockIdx.x*256 + threadIdx.x;   // < 49152
  int g = idx >> 7, e = idx & 127;
  float s = 0.f;
  for (int d = 0; d < 128; d++) s += w_ih[g*128+d]*lin_w[d*128+e];
  WcT[e*384 + g] = s;
}

// ---------------- WhhT[e][g] = w_hh[g][e] ----------------
__global__ void k_trT(const float* __restrict__ w_hh, float* __restrict__ WhhT){
  int idx = blockIdx.x*256 + threadIdx.x;   // < 49152
  int g = idx >> 7, e = idx & 127;
  WhhT[e*384 + g] = w_hh[g*128 + e];
}

// ---------------- bc = w_ih @ lin_b + b_ih ----------------
__global__ void k_bc(const float* __restrict__ w_ih, const float* __restrict__ lin_b,
                     const float* __restrict__ b_ih, float* __restrict__ bc){
  int g = blockIdx.x*128 + threadIdx.x;
  if (g >= 384) return;
  float s = b_ih[g];
  for (int d = 0; d < 128; d++) s += w_ih[g*128+d]*lin_b[d];
  bc[g] = s;
}

// =====================================================================
// fp32 GEMM (round-11 proven, verbatim): part[split][M][128] =
// A[M][Kwin] @ B[K][128]. 128x128 tile, 512 threads, micro 8x4,
// BK=32 double-buffered, compiler-scheduled. VGPR 52, 2 blocks/CU.
// FINAL: 7 structural variants (r5,r6,r8,r9,r10,r12,r13,r14,r15) all
// failed to beat this; ~55% VALUBusy is the LDS-pipe-shared cap for
// 8x4 fp32 micro-tiles (3 LDS instr / 64 VALU-cyc per kk x 8+ waves).
// =====================================================================
__global__ __launch_bounds__(512) void k_gemm_nt(const float* __restrict__ A,
    const float* __restrict__ B, float* __restrict__ part,
    int M, int lda, int kchunk)
{
  __shared__ float As[2][32*132];   // [kk][m] transposed A tile
  __shared__ float Bs[2][32*132];   // [kk][n]

  const int tid = threadIdx.x;
  const int m0  = blockIdx.x * 128;
  const int k0  = blockIdx.y * kchunk;
  const int chunks = kchunk >> 5;

  const int ar = tid >> 2;          // A row 0..127
  const int ac = tid & 3;           // A k-group
  const int br = tid >> 4;          // B kk row 0..31
  const int bc = tid & 15;          // B col group
  const int tn = tid & 31;          // cols tn*4
  const int tm = tid >> 5;          // rows tm*8 (2 values/wave -> broadcast reads)

  f32x4 pa[2], pb[2];

  auto load_regs = [&](int c){
    const float* Ab = A + (size_t)(m0 + ar)*lda + k0 + c*32 + ac*4;
    pa[0] = *(const f32x4*)(Ab);
    pa[1] = *(const f32x4*)(Ab + 16);
    const float* Bb = B + (size_t)(k0 + c*32 + br)*128 + bc*8;
    pb[0] = *(const f32x4*)(Bb);
    pb[1] = *(const f32x4*)(Bb + 4);
  };
  auto write_lds = [&](int buf){
    #pragma unroll
    for (int j = 0; j < 4; j++){
      As[buf][(ac*4 + j)*132 + ar]      = pa[0][j];
      As[buf][(ac*4 + 16 + j)*132 + ar] = pa[1][j];
    }
    *(f32x4*)&Bs[buf][br*132 + bc*8]     = pb[0];
    *(f32x4*)&Bs[buf][br*132 + bc*8 + 4] = pb[1];
  };

  f32x4 acc[8];
  #pragma unroll
  for (int i = 0; i < 8; i++) acc[i] = (f32x4){0,0,0,0};

  load_regs(0);
  write_lds(0);
  if (chunks > 1) load_regs(1);
  __syncthreads();

  for (int c = 0; c < chunks; ++c){
    int cur = c & 1;
    if (c+1 < chunks) write_lds(cur^1);
    const float* Ap = &As[cur][tm*8];
    const float* Bp = &Bs[cur][tn*4];
    #pragma unroll 8
    for (int kk = 0; kk < 32; kk++){
      f32x4 a0 = *(const f32x4*)(Ap + kk*132);
      f32x4 a1 = *(const f32x4*)(Ap + kk*132 + 4);
      f32x4 b  = *(const f32x4*)(Bp + kk*132);
      acc[0] += a0[0]*b; acc[1] += a0[1]*b; acc[2] += a0[2]*b; acc[3] += a0[3]*b;
      acc[4] += a1[0]*b; acc[5] += a1[1]*b; acc[6] += a1[2]*b; acc[7] += a1[3]*b;
    }
    if (c+2 < chunks) load_regs(c+2);
    __syncthreads();
  }

  float* P = part + ((size_t)blockIdx.y*M + m0 + tm*8)*128 + tn*4;
  #pragma unroll
  for (int i = 0; i < 8; i++)
    *(f32x4*)(P + (size_t)i*128) = acc[i];
}

// ---------------- sum splitK partials ----------------
__global__ void k_reduce(const float* __restrict__ part, float* __restrict__ out,
                         int nsplit, int stride4, int n4){
  int i = blockIdx.x*256 + threadIdx.x;
  if (i >= n4) return;
  const f32x4* p = (const f32x4*)part;
  f32x4 s = p[i];
  for (int sp = 1; sp < nsplit; sp++) s += p[(size_t)sp*stride4 + i];
  ((f32x4*)out)[i] = s;
}

// =====================================================================
// Merged gate GEMM v2: grid (M/64, 6). W read directly from L2 (64KB
// slice, reused by 64 blocks) -- no W LDS tile, LDS 34.8KB, 4 blocks/CU.
// gs<3 : gi[:, gs*128:+128]   = ah @ WcT-slice
// gs>=3: gh[:, (gs-3)*128:+128] = hc @ WhhT-slice
// =====================================================================
__global__ __launch_bounds__(256) void k_wgemm(const float* __restrict__ A0,
    const float* __restrict__ A1, const float* __restrict__ W0,
    const float* __restrict__ W1, float* __restrict__ C0, float* __restrict__ C1,
    int M)
{
  __shared__ float As[128*68];   // [e][m] (64 m used)
  const int tid = threadIdx.x;
  const int m0 = blockIdx.x * 64;
  const int gsr = blockIdx.y;
  const bool first = gsr < 3;
  const int gs = first ? gsr : gsr - 3;
  const float* A = first ? A0 : A1;
  const float* W = first ? W0 : W1;
  float* C = first ? C0 : C1;

  for (int i4 = tid; i4 < 2048; i4 += 256){
    int r = i4 >> 5, c4 = (i4 & 31) * 4;
    f32x4 v = *(const f32x4*)(A + (size_t)(m0 + r)*128 + c4);
    As[(c4+0)*68 + r] = v[0];
    As[(c4+1)*68 + r] = v[1];
    As[(c4+2)*68 + r] = v[2];
    As[(c4+3)*68 + r] = v[3];
  }
  __syncthreads();

  const int tn = tid & 31, tm = tid >> 5;
  f32x4 acc[8];
  #pragma unroll
  for (int i = 0; i < 8; i++) acc[i] = (f32x4){0,0,0,0};
  const float* Ab = &As[tm*8];
  const float* Wp = W + gs*128 + tn*4;
  #pragma unroll 4
  for (int k = 0; k < 128; k++){
    f32x4 a0 = *(const f32x4*)(Ab + k*68);
    f32x4 a1 = *(const f32x4*)(Ab + k*68 + 4);
    f32x4 b  = *(const f32x4*)(Wp + (size_t)k*384);
    #pragma unroll
    for (int i = 0; i < 4; i++) acc[i]   += a0[i]*b;
    #pragma unroll
    for (int i = 0; i < 4; i++) acc[4+i] += a1[i]*b;
  }
  float* Cp = C + (size_t)(m0 + tm*8)*384 + gs*128 + tn*4;
  #pragma unroll
  for (int i = 0; i < 8; i++)
    *(f32x4*)(Cp + (size_t)i*384) = acc[i];
}

// ---------------- GRU gates elementwise ----------------
__global__ void k_gate(const float* __restrict__ gi, const float* __restrict__ gh,
                       const float* __restrict__ bc, const float* __restrict__ bhh,
                       const float* __restrict__ hprev, float* __restrict__ hnew){
  int gid = blockIdx.x*256 + threadIdx.x;   // < 524288
  int i = gid >> 7, e = gid & 127;
  const float* gir = gi + (size_t)i*384;
  const float* ghr = gh + (size_t)i*384;
  float r = sigm(gir[e]       + bc[e]       + ghr[e]       + bhh[e]);
  float z = sigm(gir[128+e]   + bc[128+e]   + ghr[128+e]   + bhh[128+e]);
  float n = tanhf(gir[256+e]  + bc[256+e]   + r*(ghr[256+e] + bhh[256+e]));
  hnew[gid] = (1.f - z)*n + z*hprev[gid];
}

// ---------------- T[oc][dydx][q][k] = sum_c w1[oc][c][dydx]*m[4c+q][k]; ws1 = sum_c w1
__global__ void k_T(const float* __restrict__ c1w, const float* __restrict__ m,
                    float* __restrict__ T, float* __restrict__ ws1){
  int blk = blockIdx.x;          // 135 = oc*9 + dydx
  int oc = blk / 9, dydx = blk - oc*9;
  int tid = threadIdx.x;         // 512 = q*128 + k
  int q = tid >> 7, k = tid & 127;
  float acc = 0.f, accw = 0.f;
  for (int c = 0; c < 128; c++){
    float wv = c1w[(oc*128 + c)*9 + dydx];
    acc  += wv * m[(4*c + q)*128 + k];
    accw += wv;
  }
  T[((size_t)blk*4 + q)*128 + k] = acc;
  if (tid == 0) ws1[blk] = accw;
}

// ---------------- conv1 via algebraic factorization ----------------
__global__ __launch_bounds__(256) void k_conv1(const float* __restrict__ T,
    const float* __restrict__ ws1, const float* __restrict__ m,
    const float* __restrict__ b1, float* __restrict__ out1){
  int y = blockIdx.x >> 1;
  int x = ((blockIdx.x & 1) << 8) + threadIdx.x;
  float acc[15];
  #pragma unroll
  for (int oc = 0; oc < 15; oc++) acc[oc] = 0.f;
  #pragma unroll
  for (int dy = 0; dy < 3; dy++){
    int yy = y + dy - 1;
    if (yy < 0 || yy >= 512) continue;
    int q = yy >> 7;
    int jy = (yy & 127) * 4;
    #pragma unroll
    for (int dx = 0; dx < 3; dx++){
      int xx = x + dx - 1;
      if (xx < 0 || xx >= 512) continue;
      int k = xx & 127;
      int j = jy + (xx >> 7);
      float mv = m[j*128 + k];
      int dydx = dy*3 + dx;
      #pragma unroll
      for (int oc = 0; oc < 15; oc++)
        acc[oc] += T[((size_t)(oc*9 + dydx)*4 + q)*128 + k] + ws1[oc*9 + dydx] * mv;
    }
  }
  size_t o = (size_t)y*512 + x;
  #pragma unroll
  for (int oc = 0; oc < 15; oc++){
    float v = 0.5f*acc[oc] + b1[oc];
    out1[(size_t)oc*262144 + o] = v > 0.f ? v : 0.f;
  }
}

// ---------------- 3x3 conv, 4-px register blocking ----------------
template<int IC, int OC, bool RELU>
__global__ __launch_bounds__(128) void k_conv(const float* __restrict__ in,
    const float* __restrict__ w, const float* __restrict__ bias, float* __restrict__ out)
{
  __shared__ float xin[IC*10*66];
  int x0 = blockIdx.x * 64, y0 = blockIdx.y * 8;
  int tid = threadIdx.x;
  for (int i = tid; i < IC*10*66; i += 128){
    int ic = i / 660;
    int rem = i - ic*660;
    int iy = rem / 66;
    int ix = rem - iy*66;
    int gy = y0 + iy - 1, gx = x0 + ix - 1;
    float v = 0.f;
    if ((unsigned)gy < 512u && (unsigned)gx < 512u)
      v = in[(size_t)ic*262144 + (size_t)gy*512 + gx];
    xin[i] = v;
  }
  __syncthreads();
  int tx = tid & 15, ty = tid >> 4;
  float acc[OC][4];
  #pragma unroll
  for (int oc = 0; oc < OC; oc++){
    float b = bias[oc];
    acc[oc][0] = b; acc[oc][1] = b; acc[oc][2] = b; acc[oc][3] = b;
  }
  for (int ic = 0; ic < IC; ic++){
    #pragma unroll
    for (int dy = 0; dy < 3; dy++){
      const float* row = &xin[ic*660 + (ty+dy)*66 + tx*4];
      float r[6];
      #pragma unroll
      for (int j = 0; j < 6; j++) r[j] = row[j];
      #pragma unroll
      for (int dx = 0; dx < 3; dx++){
        #pragma unroll
        for (int oc = 0; oc < OC; oc++){
          float wv = w[(oc*IC + ic)*9 + dy*3 + dx];
          #pragma unroll
          for (int px = 0; px < 4; px++)
            acc[oc][px] += wv * r[dx+px];
        }
      }
    }
  }
  size_t o = (size_t)(y0 + ty)*512 + x0 + tx*4;
  #pragma unroll
  for (int oc = 0; oc < OC; oc++){
    f32x4 v;
    #pragma unroll
    for (int px = 0; px < 4; px++){
      float t = acc[oc][px];
      v[px] = RELU ? fmaxf(t, 0.f) : t;
    }
    *(f32x4*)(out + (size_t)oc*262144 + o) = v;
  }
}

// ---------------- final: sigmoid((o3 + o3^T_spatial)/2) ----------------
__global__ __launch_bounds__(256) void k_final(const float* __restrict__ o3, float* __restrict__ out){
  __shared__ float B[32*33];
  int c = blockIdx.z;
  int ty = blockIdx.y, tx = blockIdx.x;
  const float* base = o3 + (size_t)c*262144;
  int tid = threadIdx.x;
  {
    int rrow = tid >> 3, cc = (tid & 7) * 4;
    f32x4 v = *(const f32x4*)(base + (size_t)(tx*32 + rrow)*512 + ty*32 + cc);
    B[rrow*33 + cc + 0] = v[0];
    B[rrow*33 + cc + 1] = v[1];
    B[rrow*33 + cc + 2] = v[2];
    B[rrow*33 + cc + 3] = v[3];
  }
  __syncthreads();
  int i = tid >> 3, j0 = (tid & 7) * 4;
  f32x4 a = *(const f32x4*)(base + (size_t)(ty*32 + i)*512 + tx*32 + j0);
  f32x4 o;
  #pragma unroll
  for (int j = 0; j < 4; j++){
    float v = 0.5f*(a[j] + B[(j0+j)*33 + i]);
    o[j] = sigm(v);
  }
  *(f32x4*)(out + (size_t)c*262144 + (size_t)(ty*32 + i)*512 + tx*32 + j0) = o;
}

extern "C" void kernel_launch(void* const* d_in, const int* in_sizes, int n_in,
                              void* d_out, int out_size, void* d_ws, size_t ws_size,
                              hipStream_t stream) {
  (void)in_sizes; (void)n_in; (void)out_size;
  const float* adj   = (const float*)d_in[0];
  const float* mem   = (const float*)d_in[1];
  const float* emb   = (const float*)d_in[2];
  const float* lin_w = (const float*)d_in[3];
  const float* lin_b = (const float*)d_in[4];
  const float* w_ih  = (const float*)d_in[5];
  const float* w_hh  = (const float*)d_in[6];
  const float* b_ih  = (const float*)d_in[7];
  const float* b_hh  = (const float*)d_in[8];
  const float* c1w   = (const float*)d_in[9];
  const float* c1b   = (const float*)d_in[10];
  const float* c2w   = (const float*)d_in[11];
  const float* c2b   = (const float*)d_in[12];
  const float* c3w   = (const float*)d_in[13];
  const float* c3b   = (const float*)d_in[14];
  const int*   atoms = (const int*)d_in[15];
  char* ws = (char*)d_ws;

  // ---- runtime-selected splitK: 16 (needs 40.8 MB ws, proven) else 8 ----
  const bool big = ws_size >= 40780800u;
  const int  NS  = big ? 16 : 8;          // adjacency splits
  const int  NSm = big ? 64 : 32;         // membership splits
  const size_t partB = (size_t)NS * 2097152u;   // NS * 4096*128*4

  float* part = (float*)(ws + 0);
  float* gi   = (float*)(ws + 0);                 // over dead part (after k_reduce)
  float* gh   = (float*)(ws + 6291456);           // 6.29MB..12.58MB (< part end)
  float* out1 = (float*)(ws + 0);                 // 15.73MB
  float* out2 = (float*)(ws + 15728640);          // ..28.31MB
  float* out3 = (float*)(ws + 0);                 // over dead out1
  float* ah   = (float*)(ws + partB);
  float* h0   = (float*)(ws + partB + 2097152);
  float* h1   = (float*)(ws + partB + 4194304);
  char*  sm   = ws + partB + 6291456;
  float* WcT  = (float*)(sm);                     //   196,608
  float* WhhT = (float*)(sm + 196608);            //   196,608
  float* bc   = (float*)(sm + 393216);            //     1,536
  float* mbuf = (float*)(sm + 394752);            //   262,144
  float* Tbuf = (float*)(sm + 656896);            //   276,480
  float* ws1  = (float*)(sm + 933376);            //       768

  k_wc<<<192, 256, 0, stream>>>(w_ih, lin_w, WcT);
  k_trT<<<192, 256, 0, stream>>>(w_hh, WhhT);
  k_bc<<<3, 128, 0, stream>>>(w_ih, lin_b, b_ih, bc);
  k_gather<<<2048, 256, 0, stream>>>(emb, atoms, h0);

  float* hc = h0; float* hn = h1;
  for (int it = 0; it < 4; it++){
    k_gemm_nt<<<dim3(32, NS), 512, 0, stream>>>(adj, hc, part, 4096, 4096, 4096/NS);
    k_reduce<<<512, 256, 0, stream>>>(part, ah, NS, 131072, 131072);
    k_wgemm<<<dim3(64, 6), 256, 0, stream>>>(ah, hc, WcT, WhhT, gi, gh, 4096);
    k_gate<<<2048, 256, 0, stream>>>(gi, gh, bc, b_hh, hc, hn);
    float* t = hc; hc = hn; hn = t;
  }

  // hc == h0 after 4 iterations
  k_gemm_nt<<<dim3(4, NSm), 512, 0, stream>>>(mem, hc, part, 512, 4096, 4096/NSm);
  k_reduce<<<64, 256, 0, stream>>>(part, mbuf, NSm, 16384, 16384);
  k_T<<<135, 512, 0, stream>>>(c1w, mbuf, Tbuf, ws1);
  k_conv1<<<1024, 256, 0, stream>>>(Tbuf, ws1, mbuf, c1b, out1);
  k_conv<15,12,true><<<dim3(8,64), 128, 0, stream>>>(out1, c2w, c2b, out2);
  k_conv<12,12,false><<<dim3(8,64), 128, 0, stream>>>(out2, c3w, c3b, out3);
  k_final<<<dim3(16,16,12), 256, 0, stream>>>(out3, (float*)d_out);
}